// Round 8
// baseline (213.050 us; speedup 1.0000x reference)
//
#include <hip/hip_runtime.h>

typedef __bf16 bf16;
typedef __bf16 bf16x8 __attribute__((ext_vector_type(8)));
typedef __bf16 bf16x4 __attribute__((ext_vector_type(4)));
typedef float  f32x16 __attribute__((ext_vector_type(16)));
typedef unsigned int uint;
typedef unsigned int uintx4 __attribute__((ext_vector_type(4)));

#define QSCALE (0.125f * 1.44269504088896340736f)   // 1/sqrt(64) * log2(e), folded into Q

__device__ __forceinline__ void g2l16(const void* g, void* l) {
  __builtin_amdgcn_global_load_lds(
      (const __attribute__((address_space(1))) void*)g,
      (__attribute__((address_space(3))) void*)l, 16, 0, 0);
}

__device__ __forceinline__ f32x16 mfma16(bf16x8 a, bf16x8 b, f32x16 c) {
  return __builtin_amdgcn_mfma_f32_32x32x16_bf16(a, b, c, 0, 0, 0);
}

__device__ __forceinline__ uint pack_bf16(float a, float b) {
  unsigned short lo = __builtin_bit_cast(unsigned short, (bf16)a);
  unsigned short hi = __builtin_bit_cast(unsigned short, (bf16)b);
  return (uint)lo | ((uint)hi << 16);
}

// ---------------------------------------------------------------------------
// f32 -> bf16 casts. seg0: x; seg1..3: Wq/Wk/Wv -> Wqkv; seg4: Wp -> Wpb with
// the differential-combine folded into the weight:
//   Wpb[n,k]      = Wp[n,k]                      (k < 512)
//   Wpb[n,512+j]  = Wp[n,512+j] - lv*Wp[n,j]     (j < 512)
// lv recomputed inline per seg-4 wave (tiny reduction; saves a kernel).
// ---------------------------------------------------------------------------
__global__ void cast5_kernel(const float* __restrict__ x,
                             const float* __restrict__ wq, const float* __restrict__ wk,
                             const float* __restrict__ wv, const float* __restrict__ wp,
                             const float* __restrict__ lq1, const float* __restrict__ lk1,
                             const float* __restrict__ lq2, const float* __restrict__ lk2,
                             bf16* __restrict__ xb, bf16* __restrict__ wqkv,
                             bf16* __restrict__ wpb) {
  int seg = blockIdx.y;
  long i = (long)(blockIdx.x * 256 + threadIdx.x) * 8;
  const float* s; bf16* d; long n;
  if (seg == 0)      { s = x;  d = xb;  n = 4194304; }
  else if (seg == 1) { s = wq; d = wqkv;            n = 1048576; }
  else if (seg == 2) { s = wk; d = wqkv + 1048576;  n = 1048576; }
  else if (seg == 3) { s = wv; d = wqkv + 2097152;  n = 1048576; }
  else               { s = wp; d = wpb;             n = 1048576; }
  if (i >= n) return;
  float4 f0 = *(const float4*)(s + i);
  float4 f1 = *(const float4*)(s + i + 4);
  if (seg == 4 && (i & 1023) >= 512) {
    int t = threadIdx.x & 63;
    float accum = 0.f;
    for (int hh = 0; hh < 8; ++hh) {
      float v1 = lq1[hh*64 + t] * lk1[hh*64 + t];
      float v2 = lq2[hh*64 + t] * lk2[hh*64 + t];
      for (int off = 32; off; off >>= 1) {
        v1 += __shfl_xor(v1, off);
        v2 += __shfl_xor(v2, off);
      }
      accum += expf(fminf(v1, 5.f)) - expf(fminf(v2, 5.f));
    }
    float lv = accum / 8.f + 0.8f;
    float4 g0 = *(const float4*)(s + i - 512);
    float4 g1 = *(const float4*)(s + i - 508);
    f0.x -= lv * g0.x; f0.y -= lv * g0.y; f0.z -= lv * g0.z; f0.w -= lv * g0.w;
    f1.x -= lv * g1.x; f1.y -= lv * g1.y; f1.z -= lv * g1.z; f1.w -= lv * g1.w;
  }
  bf16x8 o;
  o[0] = (bf16)f0.x; o[1] = (bf16)f0.y; o[2] = (bf16)f0.z; o[3] = (bf16)f0.w;
  o[4] = (bf16)f1.x; o[5] = (bf16)f1.y; o[6] = (bf16)f1.z; o[7] = (bf16)f1.w;
  *(bf16x8*)(d + i) = o;
}

// ---------------------------------------------------------------------------
// QKV fused NT GEMM: 128x128 tile, BK=64. grid (32, 24); by = nblk>>3 picks
// Q/K/V. Q scaled by QSCALE; V written transposed into Vt[bh][d][n].
// ---------------------------------------------------------------------------
__global__ __launch_bounds__(256, 2) void gemm_qkv_kernel(
    const bf16* __restrict__ A, const bf16* __restrict__ B,
    const float* __restrict__ bias0, const float* __restrict__ bias1,
    const float* __restrict__ bias2,
    bf16* __restrict__ O0, bf16* __restrict__ O1, bf16* __restrict__ O2) {
  __shared__ __align__(16) char smem[32 * 1024];
  const int tid = threadIdx.x;
  const int w = tid >> 6, L = tid & 63;
  const int l31 = L & 31, h5 = L >> 5;
  const int m0 = blockIdx.x * 128;
  const int n0g = blockIdx.y * 128;
  const int by = n0g >> 10;
  const bf16* Bp = B + (long)by * 1048576;
  const float* biasp = (by == 0) ? bias0 : ((by == 1) ? bias1 : bias2);
  const int nloc = n0g & 1023;

  f32x16 acc[2][2];
  for (int i = 0; i < 2; ++i) for (int j = 0; j < 2; ++j)
    for (int r = 0; r < 16; ++r) acc[i][j][r] = 0.f;

  const int srow = L >> 1, spar = L & 1;
  const int wm = w >> 1, wn = w & 1;
  const int fs = (l31 * 2 + h5) * 16;

  for (int k0 = 0; k0 < 1024; k0 += 64) {
    for (int i = 0; i < 8; ++i) {
      int r = w * 8 + i;
      int rr = r & 15;
      int rowblk = rr >> 2, kst = rr & 3;
      int row = rowblk * 32 + srow;
      int kk = k0 + (kst * 2 + spar) * 8;
      const bf16* gsrc = (r < 16) ? (A + (long)(m0 + row) * 1024 + kk)
                                  : (Bp + (long)(nloc + row) * 1024 + kk);
      g2l16(gsrc, smem + r * 1024);
    }
    __syncthreads();
    for (int kst = 0; kst < 4; ++kst) {
      bf16x8 a0 = *(const bf16x8*)(smem + (((wm * 2 + 0) * 4 + kst) * 1024) + fs);
      bf16x8 a1 = *(const bf16x8*)(smem + (((wm * 2 + 1) * 4 + kst) * 1024) + fs);
      bf16x8 b0 = *(const bf16x8*)(smem + 16384 + (((wn * 2 + 0) * 4 + kst) * 1024) + fs);
      bf16x8 b1 = *(const bf16x8*)(smem + 16384 + (((wn * 2 + 1) * 4 + kst) * 1024) + fs);
      acc[0][0] = mfma16(a0, b0, acc[0][0]);
      acc[0][1] = mfma16(a0, b1, acc[0][1]);
      acc[1][0] = mfma16(a1, b0, acc[1][0]);
      acc[1][1] = mfma16(a1, b1, acc[1][1]);
    }
    __syncthreads();
  }

  if (by == 2) {
    int b = m0 >> 11;
    int nbase = (m0 & 2047);
    for (int mi = 0; mi < 2; ++mi) for (int ni = 0; ni < 2; ++ni) {
      int col = nloc + wn * 64 + ni * 32 + l31;
      int hh = col >> 6, d = col & 63;
      float bias_v = biasp[col];
      long rowbase = ((long)(b * 16 + hh) * 64 + d) * 2048
                   + nbase + wm * 64 + mi * 32 + 4 * h5;
      for (int g = 0; g < 4; ++g) {
        bf16x4 pk;
        for (int r = 0; r < 4; ++r) pk[r] = (bf16)(acc[mi][ni][g * 4 + r] + bias_v);
        *(bf16x4*)(O2 + rowbase + 8 * g) = pk;
      }
    }
  } else {
    bf16* dst = (by == 0) ? O0 : O1;
    float scale = (by == 0) ? QSCALE : 1.0f;
    for (int mi = 0; mi < 2; ++mi) for (int ni = 0; ni < 2; ++ni) {
      int col = nloc + wn * 64 + ni * 32 + l31;
      float bias_v = biasp[col];
      int row_base = m0 + wm * 64 + mi * 32 + 4 * h5;
      for (int reg = 0; reg < 16; ++reg) {
        int rowoff = (reg & 3) + 8 * (reg >> 2);
        float v = (acc[mi][ni][reg] + bias_v) * scale;
        dst[(long)(row_base + rowoff) * 1024 + col] = (bf16)v;
      }
    }
  }
}

// ---------------------------------------------------------------------------
// Projection GEMM: 64x128 tile, BK=64 (R4 version — BK=128 regressed).
// grid (64,8) = 512 blocks (2/CU), f32 out. A = Ob (combine folded into Wpb).
// ---------------------------------------------------------------------------
__global__ __launch_bounds__(256, 2) void gemm_proj_kernel(
    const bf16* __restrict__ A, const bf16* __restrict__ B,
    const float* __restrict__ bias, float* __restrict__ Of) {
  __shared__ __align__(16) char smem[24 * 1024];  // A: 0..7, B: 8..23
  const int tid = threadIdx.x;
  const int w = tid >> 6, L = tid & 63;
  const int l31 = L & 31, h5 = L >> 5;
  const int m0 = blockIdx.x * 64;
  const int nloc = blockIdx.y * 128;

  f32x16 acc[2];
  for (int i = 0; i < 2; ++i)
    for (int r = 0; r < 16; ++r) acc[i][r] = 0.f;

  const int srow = L >> 1, spar = L & 1;
  const int fs = (l31 * 2 + h5) * 16;

  for (int k0 = 0; k0 < 1024; k0 += 64) {
    for (int i = 0; i < 6; ++i) {
      int r = w * 6 + i;
      const bf16* gsrc;
      if (r < 8) {
        int rowblk = r >> 2, kst = r & 3;
        gsrc = A + (long)(m0 + rowblk * 32 + srow) * 1024 + k0 + (kst * 2 + spar) * 8;
      } else {
        int rr = r - 8;
        int rowblk = rr >> 2, kst = rr & 3;
        gsrc = B + (long)(nloc + rowblk * 32 + srow) * 1024 + k0 + (kst * 2 + spar) * 8;
      }
      g2l16(gsrc, smem + r * 1024);
    }
    __syncthreads();
    for (int kst = 0; kst < 4; ++kst) {
      bf16x8 a0 = *(const bf16x8*)(smem + ((0 * 4 + kst) * 1024) + fs);
      bf16x8 a1 = *(const bf16x8*)(smem + ((1 * 4 + kst) * 1024) + fs);
      bf16x8 bb = *(const bf16x8*)(smem + 8192 + ((w * 4 + kst) * 1024) + fs);
      acc[0] = mfma16(a0, bb, acc[0]);
      acc[1] = mfma16(a1, bb, acc[1]);
    }
    __syncthreads();
  }

  for (int mi = 0; mi < 2; ++mi) {
    int col = nloc + w * 32 + l31;
    float bias_v = bias[col];
    int row_base = m0 + mi * 32 + 4 * h5;
    for (int reg = 0; reg < 16; ++reg) {
      int rowoff = (reg & 3) + 8 * (reg >> 2);
      Of[(long)(row_base + rowoff) * 1024 + col] = acc[mi][reg] + bias_v;
    }
  }
}

// ---------------------------------------------------------------------------
// Flash attention, intra-block K-split + TRUE double-buffered staging.
// Two DISTINCT __shared__ arrays (bufA = even tiles, bufB = odd tiles) with a
// manually 2-unrolled loop and no pointer select, so LLVM alias analysis can
// prove the g2l16 prefetch (other buffer) doesn't alias the current tile's
// ds_reads -> no vmcnt(0) ordering against the prefetch; the barrier drain
// becomes ~free since each prefetch has a full compute phase in flight.
// grid (32 bh, 16 qt), 512 thr = 8 waves: waves 0-3 keys 0..1023, waves 4-7
// keys 1024..2047. Fixed-reference softmax (p = exp2(s)); halves combined
// through LDS (f32) at the end. Epilogue reuses bufA.
// ---------------------------------------------------------------------------
__global__ __launch_bounds__(512, 4) void attn_kernel(
    const bf16* __restrict__ Qb, const bf16* __restrict__ Kb,
    const bf16* __restrict__ Vt, bf16* __restrict__ Ob) {
  __shared__ __align__(16) char bufA[34816];  // staging 32KB; epilogue 34.3KB
  __shared__ __align__(16) char bufB[32768];
  const int tid = threadIdx.x, w = tid >> 6, L = tid & 63;
  const int half = w >> 2, pair = w & 3;
  const int bh = blockIdx.x, qt = blockIdx.y;
  const int b = bh >> 4, h = bh & 15;
  const int q0 = qt * 128 + pair * 32;
  const int l31 = L & 31, h5 = L >> 5;
  const int srow = L >> 1, spar = L & 1;
  const int fs = (l31 * 2 + h5) * 16;

  // Q fragments (B-operand of S^T mfma), resident for the whole K loop
  bf16x8 qf[4];
  for (int kst = 0; kst < 4; ++kst)
    qf[kst] = *(const bf16x8*)(Qb + (long)(b * 2048 + q0 + l31) * 1024 + h * 64
                               + kst * 16 + h5 * 8);

  f32x16 o[2];  // [di] : O^T rows d, cols q (unnormalized partial)
  for (int i = 0; i < 2; ++i)
    for (int r = 0; r < 16; ++r) o[i][r] = 0.f;
  float ls[4] = {0.f, 0.f, 0.f, 0.f};

  const bf16* Kbh = Kb + (long)b * 2048 * 1024 + h * 64 + (long)half * 1024 * 1024;
  const bf16* Vth = Vt + (long)bh * 64 * 2048 + half * 1024;

  auto stage = [&](int t, char* dst) {
    int n0 = t * 64;
    char* kb = dst + half * 16384;
    for (int i = 0; i < 4; ++i) {
      int r = pair * 4 + i;    // 16 regions per half, staged by its 4 waves
      if (r < 8) {
        int nkb = r >> 2, kst = r & 3;
        const bf16* g = Kbh + (long)(n0 + nkb * 32 + srow) * 1024 + (kst * 2 + spar) * 8;
        g2l16(g, kb + r * 1024);
      } else {
        int rr = r - 8, db = rr >> 2, kst = rr & 3;
        const bf16* g = Vth + (long)(db * 32 + srow) * 2048 + n0 + (kst * 2 + spar) * 8;
        g2l16(g, kb + 8192 + rr * 1024);
      }
    }
  };

  auto compute = [&](char* src) {
    char* kb = src + half * 16384;
    // S^T[key][q]
    f32x16 s[2];
    for (int i = 0; i < 2; ++i)
      for (int r = 0; r < 16; ++r) s[i][r] = 0.f;
    for (int kst = 0; kst < 4; ++kst) {
      bf16x8 k0f = *(const bf16x8*)(kb + (kst * 1024) + fs);
      bf16x8 k1f = *(const bf16x8*)(kb + ((4 + kst) * 1024) + fs);
      s[0] = mfma16(k0f, qf[kst], s[0]);
      s[1] = mfma16(k1f, qf[kst], s[1]);
    }
    // p = exp2(s); accumulate l into 4 partials
    for (int nki = 0; nki < 2; ++nki)
      for (int r = 0; r < 16; ++r) {
        float p = __builtin_amdgcn_exp2f(s[nki][r]);
        s[nki][r] = p;
        ls[r & 3] += p;
      }
    // O^T += Vt_tile · P^T (P B-fragment assembled via packs + shfl_xor(32))
    for (int kst = 0; kst < 4; ++kst) {
      bf16x8 v0 = *(const bf16x8*)(kb + 8192 + (kst * 1024) + fs);
      bf16x8 v1 = *(const bf16x8*)(kb + 8192 + ((4 + kst) * 1024) + fs);
      int nki = kst >> 1;
      int rbase = (kst & 1) * 8;
      uint p0a = pack_bf16(s[nki][rbase + 0], s[nki][rbase + 1]);
      uint p0b = pack_bf16(s[nki][rbase + 2], s[nki][rbase + 3]);
      uint p1a = pack_bf16(s[nki][rbase + 4], s[nki][rbase + 5]);
      uint p1b = pack_bf16(s[nki][rbase + 6], s[nki][rbase + 7]);
      uint t0 = h5 ? p0a : p1a;
      uint t1 = h5 ? p0b : p1b;
      uint r0 = (uint)__shfl_xor((int)t0, 32);
      uint r1 = (uint)__shfl_xor((int)t1, 32);
      uintx4 uv;
      uv.x = h5 ? r0 : p0a;
      uv.y = h5 ? r1 : p0b;
      uv.z = h5 ? p1a : r0;
      uv.w = h5 ? p1b : r1;
      bf16x8 pf = __builtin_bit_cast(bf16x8, uv);
      o[0] = mfma16(v0, pf, o[0]);
      o[1] = mfma16(v1, pf, o[1]);
    }
  };

  stage(0, bufA);
  for (int tt = 0; tt < 8; ++tt) {
    __syncthreads();                    // bufA[2tt] ready (drain ~free)
    stage(2 * tt + 1, bufB);            // prefetch odd tile
    compute(bufA);
    __syncthreads();                    // bufB[2tt+1] ready
    if (tt < 7) stage(2 * tt + 2, bufA);
    compute(bufB);
  }

  // ---- combine halves through LDS (exact f32 add), then normalize ----
  float lsum = (ls[0] + ls[1]) + (ls[2] + ls[3]);
  float lcol = lsum + __shfl_xor(lsum, 32);  // per-col l of this half
  if (half) {
    float* dstO = (float*)bufA + pair * 2112;   // stride 33 dwords: bank-free
    for (int di = 0; di < 2; ++di)
      for (int r = 0; r < 16; ++r) dstO[L * 33 + di * 16 + r] = o[di][r];
    if (h5 == 0) ((float*)(bufA + 33792))[pair * 32 + l31] = lcol;
  }
  __syncthreads();
  float linv = 0.f;
  if (!half) {
    float* srcO = (float*)bufA + pair * 2112;
    for (int di = 0; di < 2; ++di)
      for (int r = 0; r < 16; ++r) o[di][r] += srcO[L * 33 + di * 16 + r];
    float lother = ((float*)(bufA + 33792))[pair * 32 + l31];
    linv = 1.f / (lcol + lother);
  }
  __syncthreads();
  if (!half) {
    // O^T/l -> per-wave LDS tile [32 q][68 d-stride] -> coalesced store
    char* ot = bufA + pair * 4352;
    for (int di = 0; di < 2; ++di)
      for (int g = 0; g < 4; ++g) {
        bf16x4 pk;
        for (int r = 0; r < 4; ++r)
          pk[r] = (bf16)(o[di][g * 4 + r] * linv);
        int d0 = di * 32 + g * 8 + h5 * 4;
        *(bf16x4*)(ot + (l31 * 68 + d0) * 2) = pk;
      }
    for (int i = 0; i < 4; ++i) {
      int qloc = (L >> 3) + i * 8;
      int cc = L & 7;
      bf16x8 vv = *(const bf16x8*)(ot + (qloc * 68 + cc * 8) * 2);
      *(bf16x8*)(Ob + (long)(b * 2048 + q0 + qloc) * 1024 + h * 64 + cc * 8) = vv;
    }
  }
}

// ---------------------------------------------------------------------------
extern "C" void kernel_launch(void* const* d_in, const int* in_sizes, int n_in,
                              void* d_out, int out_size, void* d_ws, size_t ws_size,
                              hipStream_t stream) {
  const float* x   = (const float*)d_in[0];
  const float* Wq  = (const float*)d_in[1];
  const float* bq  = (const float*)d_in[2];
  const float* Wk  = (const float*)d_in[3];
  const float* bk  = (const float*)d_in[4];
  const float* Wv  = (const float*)d_in[5];
  const float* bv  = (const float*)d_in[6];
  const float* Wp  = (const float*)d_in[7];
  const float* bp  = (const float*)d_in[8];
  const float* lq1 = (const float*)d_in[9];
  const float* lk1 = (const float*)d_in[10];
  const float* lq2 = (const float*)d_in[11];
  const float* lk2 = (const float*)d_in[12];
  float* out = (float*)d_out;

  // ws layout: pad | xb(8MB) | Wqkv(6MB) | Wpb(2MB) | Vt(8MB) | Ob(8MB)
  char* ws = (char*)d_ws;
  bf16* xb   = (bf16*)(ws + 1024);
  bf16* Wqkv = xb + (long)4096 * 1024;
  bf16* Wpb  = Wqkv + (long)3 * 1024 * 1024;
  bf16* Vt   = Wpb + (long)1024 * 1024;       // [32 bh][64 d][2048 n]
  bf16* Ob   = Vt + (long)4096 * 1024;
  // Q/K bf16 tensors live in d_out (16MB); dead before final GEMM writes it
  bf16* Qb = (bf16*)d_out;
  bf16* Kb = Qb + (long)4096 * 1024;

  cast5_kernel<<<dim3(2048, 5), 256, 0, stream>>>(
      x, Wq, Wk, Wv, Wp, lq1, lk1, lq2, lk2, xb, Wqkv, Wpb);
  gemm_qkv_kernel<<<dim3(32, 24), 256, 0, stream>>>(
      xb, Wqkv, bq, bk, bv, Qb, Kb, Vt);
  attn_kernel<<<dim3(32, 16), 512, 0, stream>>>(Qb, Kb, Vt, Ob);
  gemm_proj_kernel<<<dim3(64, 8), 256, 0, stream>>>(Ob, Wpb, bp, out);
}

// Round 9
// 202.990 us; speedup vs baseline: 1.0496x; 1.0496x over previous
//
#include <hip/hip_runtime.h>

typedef __bf16 bf16;
typedef __bf16 bf16x8 __attribute__((ext_vector_type(8)));
typedef __bf16 bf16x4 __attribute__((ext_vector_type(4)));
typedef float  f32x16 __attribute__((ext_vector_type(16)));
typedef unsigned int uint;
typedef unsigned int uintx4 __attribute__((ext_vector_type(4)));

#define QSCALE (0.125f * 1.44269504088896340736f)   // 1/sqrt(64) * log2(e), folded into Q

__device__ __forceinline__ void g2l16(const void* g, void* l) {
  __builtin_amdgcn_global_load_lds(
      (const __attribute__((address_space(1))) void*)g,
      (__attribute__((address_space(3))) void*)l, 16, 0, 0);
}

__device__ __forceinline__ f32x16 mfma16(bf16x8 a, bf16x8 b, f32x16 c) {
  return __builtin_amdgcn_mfma_f32_32x32x16_bf16(a, b, c, 0, 0, 0);
}

__device__ __forceinline__ uint pack_bf16(float a, float b) {
  unsigned short lo = __builtin_bit_cast(unsigned short, (bf16)a);
  unsigned short hi = __builtin_bit_cast(unsigned short, (bf16)b);
  return (uint)lo | ((uint)hi << 16);
}

// ---------------------------------------------------------------------------
// f32 -> bf16 casts. seg0: x; seg1..3: Wq/Wk/Wv -> Wqkv; seg4: Wp -> Wpb with
// the differential-combine folded into the weight:
//   Wpb[n,k]      = Wp[n,k]                      (k < 512)
//   Wpb[n,512+j]  = Wp[n,512+j] - lv*Wp[n,j]     (j < 512)
// lv recomputed inline per seg-4 wave (tiny reduction; saves a kernel).
// ---------------------------------------------------------------------------
__global__ void cast5_kernel(const float* __restrict__ x,
                             const float* __restrict__ wq, const float* __restrict__ wk,
                             const float* __restrict__ wv, const float* __restrict__ wp,
                             const float* __restrict__ lq1, const float* __restrict__ lk1,
                             const float* __restrict__ lq2, const float* __restrict__ lk2,
                             bf16* __restrict__ xb, bf16* __restrict__ wqkv,
                             bf16* __restrict__ wpb) {
  int seg = blockIdx.y;
  long i = (long)(blockIdx.x * 256 + threadIdx.x) * 8;
  const float* s; bf16* d; long n;
  if (seg == 0)      { s = x;  d = xb;  n = 4194304; }
  else if (seg == 1) { s = wq; d = wqkv;            n = 1048576; }
  else if (seg == 2) { s = wk; d = wqkv + 1048576;  n = 1048576; }
  else if (seg == 3) { s = wv; d = wqkv + 2097152;  n = 1048576; }
  else               { s = wp; d = wpb;             n = 1048576; }
  if (i >= n) return;
  float4 f0 = *(const float4*)(s + i);
  float4 f1 = *(const float4*)(s + i + 4);
  if (seg == 4 && (i & 1023) >= 512) {
    int t = threadIdx.x & 63;
    float accum = 0.f;
    for (int hh = 0; hh < 8; ++hh) {
      float v1 = lq1[hh*64 + t] * lk1[hh*64 + t];
      float v2 = lq2[hh*64 + t] * lk2[hh*64 + t];
      for (int off = 32; off; off >>= 1) {
        v1 += __shfl_xor(v1, off);
        v2 += __shfl_xor(v2, off);
      }
      accum += expf(fminf(v1, 5.f)) - expf(fminf(v2, 5.f));
    }
    float lv = accum / 8.f + 0.8f;
    float4 g0 = *(const float4*)(s + i - 512);
    float4 g1 = *(const float4*)(s + i - 508);
    f0.x -= lv * g0.x; f0.y -= lv * g0.y; f0.z -= lv * g0.z; f0.w -= lv * g0.w;
    f1.x -= lv * g1.x; f1.y -= lv * g1.y; f1.z -= lv * g1.z; f1.w -= lv * g1.w;
  }
  bf16x8 o;
  o[0] = (bf16)f0.x; o[1] = (bf16)f0.y; o[2] = (bf16)f0.z; o[3] = (bf16)f0.w;
  o[4] = (bf16)f1.x; o[5] = (bf16)f1.y; o[6] = (bf16)f1.z; o[7] = (bf16)f1.w;
  *(bf16x8*)(d + i) = o;
}

// ---------------------------------------------------------------------------
// QKV fused NT GEMM: 128x128 tile, BK=64. grid (32, 24); by = nblk>>3 picks
// Q/K/V. Q scaled by QSCALE. V written transposed AND key-permuted into
// Vt[bh][d][slot]: within each 64-token tile, token tau = 8*Qp + 4*h5 + r
// goes to slot = 16*(Qp>>1) + 8*h5 + 4*(Qp&1) + r.  This permutation makes
// the attention PV B-fragment equal each lane's own 8 consecutive S-regs
// (no cross-lane shuffles) while A-fragment reads stay unchanged.
// ---------------------------------------------------------------------------
__global__ __launch_bounds__(256, 2) void gemm_qkv_kernel(
    const bf16* __restrict__ A, const bf16* __restrict__ B,
    const float* __restrict__ bias0, const float* __restrict__ bias1,
    const float* __restrict__ bias2,
    bf16* __restrict__ O0, bf16* __restrict__ O1, bf16* __restrict__ O2) {
  __shared__ __align__(16) char smem[32 * 1024];
  const int tid = threadIdx.x;
  const int w = tid >> 6, L = tid & 63;
  const int l31 = L & 31, h5 = L >> 5;
  const int m0 = blockIdx.x * 128;
  const int n0g = blockIdx.y * 128;
  const int by = n0g >> 10;
  const bf16* Bp = B + (long)by * 1048576;
  const float* biasp = (by == 0) ? bias0 : ((by == 1) ? bias1 : bias2);
  const int nloc = n0g & 1023;

  f32x16 acc[2][2];
  for (int i = 0; i < 2; ++i) for (int j = 0; j < 2; ++j)
    for (int r = 0; r < 16; ++r) acc[i][j][r] = 0.f;

  const int srow = L >> 1, spar = L & 1;
  const int wm = w >> 1, wn = w & 1;
  const int fs = (l31 * 2 + h5) * 16;

  for (int k0 = 0; k0 < 1024; k0 += 64) {
    for (int i = 0; i < 8; ++i) {
      int r = w * 8 + i;
      int rr = r & 15;
      int rowblk = rr >> 2, kst = rr & 3;
      int row = rowblk * 32 + srow;
      int kk = k0 + (kst * 2 + spar) * 8;
      const bf16* gsrc = (r < 16) ? (A + (long)(m0 + row) * 1024 + kk)
                                  : (Bp + (long)(nloc + row) * 1024 + kk);
      g2l16(gsrc, smem + r * 1024);
    }
    __syncthreads();
    for (int kst = 0; kst < 4; ++kst) {
      bf16x8 a0 = *(const bf16x8*)(smem + (((wm * 2 + 0) * 4 + kst) * 1024) + fs);
      bf16x8 a1 = *(const bf16x8*)(smem + (((wm * 2 + 1) * 4 + kst) * 1024) + fs);
      bf16x8 b0 = *(const bf16x8*)(smem + 16384 + (((wn * 2 + 0) * 4 + kst) * 1024) + fs);
      bf16x8 b1 = *(const bf16x8*)(smem + 16384 + (((wn * 2 + 1) * 4 + kst) * 1024) + fs);
      acc[0][0] = mfma16(a0, b0, acc[0][0]);
      acc[0][1] = mfma16(a0, b1, acc[0][1]);
      acc[1][0] = mfma16(a1, b0, acc[1][0]);
      acc[1][1] = mfma16(a1, b1, acc[1][1]);
    }
    __syncthreads();
  }

  if (by == 2) {
    int b = m0 >> 11;
    int nbase = (m0 & 2047);
    for (int mi = 0; mi < 2; ++mi) for (int ni = 0; ni < 2; ++ni) {
      int col = nloc + wn * 64 + ni * 32 + l31;
      int hh = col >> 6, d = col & 63;
      float bias_v = biasp[col];
      long rowbase = ((long)(b * 16 + hh) * 64 + d) * 2048 + nbase + wm * 64;
      for (int g = 0; g < 4; ++g) {
        bf16x4 pk;
        for (int r = 0; r < 4; ++r) pk[r] = (bf16)(acc[mi][ni][g * 4 + r] + bias_v);
        int Qp = mi * 4 + g;
        int slot = (Qp >> 1) * 16 + h5 * 8 + (Qp & 1) * 4;
        *(bf16x4*)(O2 + rowbase + slot) = pk;
      }
    }
  } else {
    bf16* dst = (by == 0) ? O0 : O1;
    float scale = (by == 0) ? QSCALE : 1.0f;
    for (int mi = 0; mi < 2; ++mi) for (int ni = 0; ni < 2; ++ni) {
      int col = nloc + wn * 64 + ni * 32 + l31;
      float bias_v = biasp[col];
      int row_base = m0 + wm * 64 + mi * 32 + 4 * h5;
      for (int reg = 0; reg < 16; ++reg) {
        int rowoff = (reg & 3) + 8 * (reg >> 2);
        float v = (acc[mi][ni][reg] + bias_v) * scale;
        dst[(long)(row_base + rowoff) * 1024 + col] = (bf16)v;
      }
    }
  }
}

// ---------------------------------------------------------------------------
// Projection GEMM: 64x128 tile, BK=64. grid (64,8) = 512 blocks (2/CU),
// f32 out. A = Ob (combine folded into Wpb).
// ---------------------------------------------------------------------------
__global__ __launch_bounds__(256, 2) void gemm_proj_kernel(
    const bf16* __restrict__ A, const bf16* __restrict__ B,
    const float* __restrict__ bias, float* __restrict__ Of) {
  __shared__ __align__(16) char smem[24 * 1024];  // A: 0..7, B: 8..23
  const int tid = threadIdx.x;
  const int w = tid >> 6, L = tid & 63;
  const int l31 = L & 31, h5 = L >> 5;
  const int m0 = blockIdx.x * 64;
  const int nloc = blockIdx.y * 128;

  f32x16 acc[2];
  for (int i = 0; i < 2; ++i)
    for (int r = 0; r < 16; ++r) acc[i][r] = 0.f;

  const int srow = L >> 1, spar = L & 1;
  const int fs = (l31 * 2 + h5) * 16;

  for (int k0 = 0; k0 < 1024; k0 += 64) {
    for (int i = 0; i < 6; ++i) {
      int r = w * 6 + i;
      const bf16* gsrc;
      if (r < 8) {
        int rowblk = r >> 2, kst = r & 3;
        gsrc = A + (long)(m0 + rowblk * 32 + srow) * 1024 + k0 + (kst * 2 + spar) * 8;
      } else {
        int rr = r - 8;
        int rowblk = rr >> 2, kst = rr & 3;
        gsrc = B + (long)(nloc + rowblk * 32 + srow) * 1024 + k0 + (kst * 2 + spar) * 8;
      }
      g2l16(gsrc, smem + r * 1024);
    }
    __syncthreads();
    for (int kst = 0; kst < 4; ++kst) {
      bf16x8 a0 = *(const bf16x8*)(smem + ((0 * 4 + kst) * 1024) + fs);
      bf16x8 a1 = *(const bf16x8*)(smem + ((1 * 4 + kst) * 1024) + fs);
      bf16x8 bb = *(const bf16x8*)(smem + 8192 + ((w * 4 + kst) * 1024) + fs);
      acc[0] = mfma16(a0, bb, acc[0]);
      acc[1] = mfma16(a1, bb, acc[1]);
    }
    __syncthreads();
  }

  for (int mi = 0; mi < 2; ++mi) {
    int col = nloc + w * 32 + l31;
    float bias_v = bias[col];
    int row_base = m0 + mi * 32 + 4 * h5;
    for (int reg = 0; reg < 16; ++reg) {
      int rowoff = (reg & 3) + 8 * (reg >> 2);
      Of[(long)(row_base + rowoff) * 1024 + col] = acc[mi][reg] + bias_v;
    }
  }
}

// ---------------------------------------------------------------------------
// Flash attention, intra-block K-split (64-key tiles, 16 iters). grid
// (32 bh, 16 qt), 512 thr = 8 waves: waves 0-3 keys 0..1023, waves 4-7 keys
// 1024..2047; wave pair (w, w+4) shares a 32-query range. Fixed-reference
// softmax (p = exp2(s)); halves combined through LDS (f32) at the end.
// Vt is key-permuted (see gemm_qkv_kernel), so the PV B-fragment is each
// lane's own 8 consecutive S-regs: zero cross-lane ops in the K-loop.
// ---------------------------------------------------------------------------
__global__ __launch_bounds__(512, 4) void attn_kernel(
    const bf16* __restrict__ Qb, const bf16* __restrict__ Kb,
    const bf16* __restrict__ Vt, bf16* __restrict__ Ob) {
  // staging: [half][K 8KB | V 8KB] = 32KB.  epilogue (reuses same bytes):
  // O-exchange 4 pairs x 8448B = 33792, l at 33792..34304, transpose 4x4352.
  __shared__ __align__(16) char smem[34816];
  const int tid = threadIdx.x, w = tid >> 6, L = tid & 63;
  const int half = w >> 2, pair = w & 3;
  const int bh = blockIdx.x, qt = blockIdx.y;
  const int b = bh >> 4, h = bh & 15;
  const int q0 = qt * 128 + pair * 32;
  const int l31 = L & 31, h5 = L >> 5;
  const int srow = L >> 1, spar = L & 1;
  const int fs = (l31 * 2 + h5) * 16;
  char* kbase = smem + half * 16384;

  // Q fragments (B-operand of S^T mfma), resident for the whole K loop
  bf16x8 qf[4];
  for (int kst = 0; kst < 4; ++kst)
    qf[kst] = *(const bf16x8*)(Qb + (long)(b * 2048 + q0 + l31) * 1024 + h * 64
                               + kst * 16 + h5 * 8);

  f32x16 o[2];  // [di] : O^T rows d, cols q (unnormalized partial)
  for (int i = 0; i < 2; ++i)
    for (int r = 0; r < 16; ++r) o[i][r] = 0.f;
  float ls[4] = {0.f, 0.f, 0.f, 0.f};  // 4-way partial l

  const bf16* Kbh = Kb + (long)b * 2048 * 1024 + h * 64 + (long)half * 1024 * 1024;
  const bf16* Vth = Vt + (long)bh * 64 * 2048 + half * 1024;

  for (int t = 0; t < 16; ++t) {
    int n0 = t * 64;
    for (int i = 0; i < 4; ++i) {
      int r = pair * 4 + i;    // 16 regions per half, staged by its 4 waves
      if (r < 8) {
        int nkb = r >> 2, kst = r & 3;
        const bf16* g = Kbh + (long)(n0 + nkb * 32 + srow) * 1024 + (kst * 2 + spar) * 8;
        g2l16(g, kbase + r * 1024);
      } else {
        int rr = r - 8, db = rr >> 2, kst = rr & 3;
        const bf16* g = Vth + (long)(db * 32 + srow) * 2048 + n0 + (kst * 2 + spar) * 8;
        g2l16(g, kbase + 8192 + rr * 1024);
      }
    }
    __syncthreads();

    // S^T[key][q]
    f32x16 s[2];
    for (int i = 0; i < 2; ++i)
      for (int r = 0; r < 16; ++r) s[i][r] = 0.f;
    for (int kst = 0; kst < 4; ++kst) {
      bf16x8 k0f = *(const bf16x8*)(kbase + (kst * 1024) + fs);
      bf16x8 k1f = *(const bf16x8*)(kbase + ((4 + kst) * 1024) + fs);
      s[0] = mfma16(k0f, qf[kst], s[0]);
      s[1] = mfma16(k1f, qf[kst], s[1]);
    }

    // p = exp2(s); accumulate l into 4 partials
    for (int nki = 0; nki < 2; ++nki)
      for (int r = 0; r < 16; ++r) {
        float p = __builtin_amdgcn_exp2f(s[nki][r]);
        s[nki][r] = p;
        ls[r & 3] += p;
      }

    // O^T += Vt_tile · P^T.  Vt global layout is key-permuted so that the
    // B-fragment for kst is exactly s[kst>>1][8*(kst&1) + 0..7] in order.
    for (int kst = 0; kst < 4; ++kst) {
      bf16x8 v0 = *(const bf16x8*)(kbase + 8192 + (kst * 1024) + fs);
      bf16x8 v1 = *(const bf16x8*)(kbase + 8192 + ((4 + kst) * 1024) + fs);
      int nki = kst >> 1;
      int rbase = (kst & 1) * 8;
      uintx4 uv;
      uv.x = pack_bf16(s[nki][rbase + 0], s[nki][rbase + 1]);
      uv.y = pack_bf16(s[nki][rbase + 2], s[nki][rbase + 3]);
      uv.z = pack_bf16(s[nki][rbase + 4], s[nki][rbase + 5]);
      uv.w = pack_bf16(s[nki][rbase + 6], s[nki][rbase + 7]);
      bf16x8 pf = __builtin_bit_cast(bf16x8, uv);
      o[0] = mfma16(v0, pf, o[0]);
      o[1] = mfma16(v1, pf, o[1]);
    }
    __syncthreads();
  }

  // ---- combine halves through LDS (exact f32 add), then normalize ----
  float lsum = (ls[0] + ls[1]) + (ls[2] + ls[3]);
  float lcol = lsum + __shfl_xor(lsum, 32);  // per-col l of this half
  if (half) {
    float* dstO = (float*)smem + pair * 2112;   // stride 33 dwords: bank-free
    for (int di = 0; di < 2; ++di)
      for (int r = 0; r < 16; ++r) dstO[L * 33 + di * 16 + r] = o[di][r];
    if (h5 == 0) ((float*)(smem + 33792))[pair * 32 + l31] = lcol;
  }
  __syncthreads();
  float linv = 0.f;
  if (!half) {
    float* srcO = (float*)smem + pair * 2112;
    for (int di = 0; di < 2; ++di)
      for (int r = 0; r < 16; ++r) o[di][r] += srcO[L * 33 + di * 16 + r];
    float lother = ((float*)(smem + 33792))[pair * 32 + l31];
    linv = 1.f / (lcol + lother);
  }
  __syncthreads();
  if (!half) {
    // O^T/l -> per-wave LDS tile [32 q][68 d-stride] -> coalesced store
    char* ot = smem + pair * 4352;
    for (int di = 0; di < 2; ++di)
      for (int g = 0; g < 4; ++g) {
        bf16x4 pk;
        for (int r = 0; r < 4; ++r)
          pk[r] = (bf16)(o[di][g * 4 + r] * linv);
        int d0 = di * 32 + g * 8 + h5 * 4;
        *(bf16x4*)(ot + (l31 * 68 + d0) * 2) = pk;
      }
    for (int i = 0; i < 4; ++i) {
      int qloc = (L >> 3) + i * 8;
      int cc = L & 7;
      bf16x8 vv = *(const bf16x8*)(ot + (qloc * 68 + cc * 8) * 2);
      *(bf16x8*)(Ob + (long)(b * 2048 + q0 + qloc) * 1024 + h * 64 + cc * 8) = vv;
    }
  }
}

// ---------------------------------------------------------------------------
extern "C" void kernel_launch(void* const* d_in, const int* in_sizes, int n_in,
                              void* d_out, int out_size, void* d_ws, size_t ws_size,
                              hipStream_t stream) {
  const float* x   = (const float*)d_in[0];
  const float* Wq  = (const float*)d_in[1];
  const float* bq  = (const float*)d_in[2];
  const float* Wk  = (const float*)d_in[3];
  const float* bk  = (const float*)d_in[4];
  const float* Wv  = (const float*)d_in[5];
  const float* bv  = (const float*)d_in[6];
  const float* Wp  = (const float*)d_in[7];
  const float* bp  = (const float*)d_in[8];
  const float* lq1 = (const float*)d_in[9];
  const float* lk1 = (const float*)d_in[10];
  const float* lq2 = (const float*)d_in[11];
  const float* lk2 = (const float*)d_in[12];
  float* out = (float*)d_out;

  // ws layout: pad | xb(8MB) | Wqkv(6MB) | Wpb(2MB) | Vt(8MB) | Ob(8MB)
  char* ws = (char*)d_ws;
  bf16* xb   = (bf16*)(ws + 1024);
  bf16* Wqkv = xb + (long)4096 * 1024;
  bf16* Wpb  = Wqkv + (long)3 * 1024 * 1024;
  bf16* Vt   = Wpb + (long)1024 * 1024;       // [32 bh][64 d][2048 slot]
  bf16* Ob   = Vt + (long)4096 * 1024;
  // Q/K bf16 tensors live in d_out (16MB); dead before final GEMM writes it
  bf16* Qb = (bf16*)d_out;
  bf16* Kb = Qb + (long)4096 * 1024;

  cast5_kernel<<<dim3(2048, 5), 256, 0, stream>>>(
      x, Wq, Wk, Wv, Wp, lq1, lk1, lq2, lk2, xb, Wqkv, Wpb);
  gemm_qkv_kernel<<<dim3(32, 24), 256, 0, stream>>>(
      xb, Wqkv, bq, bk, bv, Qb, Kb, Vt);
  attn_kernel<<<dim3(32, 16), 512, 0, stream>>>(Qb, Kb, Vt, Ob);
  gemm_proj_kernel<<<dim3(64, 8), 256, 0, stream>>>(Ob, Wpb, bp, out);
}